// Round 5
// baseline (431.961 us; speedup 1.0000x reference)
//
#include <hip/hip_runtime.h>
#include <stdint.h>

// NARM fused pipeline v5 for MI355X (gfx950).
//   k_prep : zero carry slots + cum; cast A1/A2 -> bf16
//   k_xcast: cast x (fp32) -> xb (bf16) once
//   k_scan : dual-GRU recurrence; x A-frags loaded straight from global (L1)
//            2 steps ahead; h through conflict-free k-chunk-major LDS layout
//   k_score: grid (tc,2), 512 thr; A1/A2 bf16 staged once per block
//   k_cum  : LDS-staged cumsum of score*h_l, capture t in [L_b-4, L_b-1], +h_g

typedef __attribute__((ext_vector_type(8))) short short8;
typedef __attribute__((ext_vector_type(4))) float float4v;

// exec+LDS barrier without the full vmcnt drain of __syncthreads()
#define LDS_BARRIER() asm volatile("s_waitcnt lgkmcnt(0)\n\ts_barrier" ::: "memory")

__device__ inline float bf2f(unsigned short u){
  union { unsigned int i; float f; } v; v.i = ((unsigned int)u) << 16; return v.f;
}
__device__ inline unsigned short f2bf(float f){
  union { float f; unsigned int i; } v; v.f = f;
  unsigned int x = v.i;
  return (unsigned short)((x + 0x7fffu + ((x >> 16) & 1u)) >> 16);
}
__device__ inline unsigned int pack2(float a, float b){
  return (unsigned int)f2bf(a) | ((unsigned int)f2bf(b) << 16);
}
__device__ inline float sigm(float x){ return __builtin_amdgcn_rcpf(1.0f + __expf(-x)); }

// ---------------- K0: prep ----------------
__global__ void k_prep(unsigned short* hl_slot, unsigned short* hg_slot, float* cum,
                       const float* A1, const float* A2, unsigned short* a12)
{
  int i = blockIdx.x * blockDim.x + threadIdx.x;   // grid 512*256 = 131072
  hl_slot[i] = 0;
  hg_slot[i] = 0;
  cum[i] = 0.0f;
  if (i < 32768) {
    a12[i] = f2bf((i < 16384) ? A1[i] : A2[i - 16384]);
  }
}

// ---------------- K0b: x -> bf16 ----------------
// grid 12800 x 256: thread converts 8 floats (two float4) -> 8 bf16
__global__ void k_xcast(const float* __restrict__ x, unsigned short* __restrict__ xb)
{
  size_t i = (size_t)blockIdx.x * blockDim.x + threadIdx.x;   // 0..3276799
  const float4* xf = (const float4*)x;
  float4 a = xf[2 * i], b = xf[2 * i + 1];
  short8 o;
  o[0]=(short)f2bf(a.x); o[1]=(short)f2bf(a.y); o[2]=(short)f2bf(a.z); o[3]=(short)f2bf(a.w);
  o[4]=(short)f2bf(b.x); o[5]=(short)f2bf(b.y); o[6]=(short)f2bf(b.z); o[7]=(short)f2bf(b.w);
  *(short8*)(xb + i * 8) = o;
}

// ---------------- K1: fused dual-GRU scan ----------------
// grid 128 = (64 batch-groups x 2 GRUs), block 512 (8 waves, 16 cols each).
// h LDS layout (per buffer, 2048 shorts): idx(m,k) = (k>>3)*128 + m*8 + (k&7)
//   -> wave A-frag read: ds_read_b128 at base + lane*16B (conflict-free)
__global__ __launch_bounds__(512, 2) void k_scan(
    const unsigned short* __restrict__ xb,
    const float* __restrict__ Wih_g, const float* __restrict__ Whh_g,
    const float* __restrict__ bih_g, const float* __restrict__ bhh_g,
    const float* __restrict__ Wih_l, const float* __restrict__ Whh_l,
    const float* __restrict__ bih_l, const float* __restrict__ bhh_l,
    unsigned short* __restrict__ hl_seq, unsigned short* __restrict__ hg_seq,
    int tc, int t0)
{
  __shared__ __align__(16) unsigned short hb[2][2048];
  int tid = threadIdx.x;
  int w = tid >> 6, L = tid & 63, l15 = L & 15, q = L >> 4;
  int gru = blockIdx.x & 1;                 // 0 = g, 1 = l
  int b0 = (blockIdx.x >> 1) * 16;
  const float* Wih = gru ? Wih_l : Wih_g;
  const float* Whh = gru ? Whh_l : Whh_g;
  const float* bih = gru ? bih_l : bih_g;
  const float* bhh = gru ? bhh_l : bhh_g;
  unsigned short* myseq = gru ? hl_seq : hg_seq;

  int col = w * 16 + l15;                   // this lane's output column

  // register-resident weight B-fragments (fp32 -> bf16 once per launch)
  short8 Wi[3][4], Wh[3][4];
  #pragma unroll
  for (int G = 0; G < 3; G++) {
    int row = G * 128 + col;
    #pragma unroll
    for (int kf = 0; kf < 4; kf++) {
      const float4* p0 = (const float4*)(Wih + (size_t)row * 128 + kf * 32 + q * 8);
      const float4* p1 = (const float4*)(Whh + (size_t)row * 128 + kf * 32 + q * 8);
      float4 a0 = p0[0], a1 = p0[1], b0f = p1[0], b1f = p1[1];
      short8 si, sh;
      si[0]=(short)f2bf(a0.x); si[1]=(short)f2bf(a0.y); si[2]=(short)f2bf(a0.z); si[3]=(short)f2bf(a0.w);
      si[4]=(short)f2bf(a1.x); si[5]=(short)f2bf(a1.y); si[6]=(short)f2bf(a1.z); si[7]=(short)f2bf(a1.w);
      sh[0]=(short)f2bf(b0f.x); sh[1]=(short)f2bf(b0f.y); sh[2]=(short)f2bf(b0f.z); sh[3]=(short)f2bf(b0f.w);
      sh[4]=(short)f2bf(b1f.x); sh[5]=(short)f2bf(b1f.y); sh[6]=(short)f2bf(b1f.z); sh[7]=(short)f2bf(b1f.w);
      Wi[G][kf] = si; Wh[G][kf] = sh;
    }
  }
  float br  = bih[col]       + bhh[col];
  float bz  = bih[128 + col] + bhh[128 + col];
  float bin = bih[256 + col];               // bhh_n stays inside r*( ) per PyTorch GRU
  float bnh = bhh[256 + col];

  // init h from carry slot (zeroed by k_prep for chunk 0)
  float hold[4];
  #pragma unroll
  for (int r = 0; r < 4; r++) {
    int m = q * 4 + r;
    unsigned short u = myseq[((size_t)(tc - 1) * 1024 + b0 + m) * 128 + col];
    hold[r] = bf2f(u);
    hb[0][(col >> 3) * 128 + m * 8 + (col & 7)] = u;
  }

  // x A-fragment prefetch registers (2-deep)
  short8 x2[2][4];
  const unsigned short* xlane = xb + ((size_t)b0 + l15) * 128 + q * 8;
  {
    const unsigned short* px = xlane + (size_t)t0 * 131072;
    #pragma unroll
    for (int kf = 0; kf < 4; kf++) x2[0][kf] = *(const short8*)(px + kf * 32);
    int t1 = t0 + (tc > 1 ? 1 : 0);
    const unsigned short* py = xlane + (size_t)t1 * 131072;
    #pragma unroll
    for (int kf = 0; kf < 4; kf++) x2[1][kf] = *(const short8*)(py + kf * 32);
  }
  __syncthreads();

  // hoisted output pointer: stores at opq[r*128] with immediate offsets
  unsigned short* opq = myseq + ((size_t)(b0 + q * 4)) * 128 + col;
  unsigned int* hbw = (unsigned int*)&hb[0][0];
  int wdw = (2 * w + (l15 >> 3)) * 64 + ((l15 & 6) >> 1);  // dword base for packed write
  bool wlane = (L & 1) == 0;

  auto step = [&](int s, int pin, int pout) {
    // h A-fragments: conflict-free contiguous read
    short8 Ah[4];
    #pragma unroll
    for (int kf = 0; kf < 4; kf++)
      Ah[kf] = *(const short8*)&hb[pin][(kf * 4 + q) * 128 + l15 * 8];

    // x-side MFMAs first (operands already in registers, independent of h)
    float4v rx = (float4v){0.f,0.f,0.f,0.f}, zx = rx, nx = rx;
    #pragma unroll
    for (int kf = 0; kf < 4; kf++) rx = __builtin_amdgcn_mfma_f32_16x16x32_bf16(x2[pin][kf], Wi[0][kf], rx, 0,0,0);
    #pragma unroll
    for (int kf = 0; kf < 4; kf++) zx = __builtin_amdgcn_mfma_f32_16x16x32_bf16(x2[pin][kf], Wi[1][kf], zx, 0,0,0);
    #pragma unroll
    for (int kf = 0; kf < 4; kf++) nx = __builtin_amdgcn_mfma_f32_16x16x32_bf16(x2[pin][kf], Wi[2][kf], nx, 0,0,0);

    // refill this x buffer for step s+2 (registers free after the MFMAs above)
    {
      int t2 = t0 + (s + 2 < tc ? s + 2 : tc - 1);
      const unsigned short* px = xlane + (size_t)t2 * 131072;
      #pragma unroll
      for (int kf = 0; kf < 4; kf++) x2[pin][kf] = *(const short8*)(px + kf * 32);
    }

    // h-side MFMAs
    float4v rh = (float4v){0.f,0.f,0.f,0.f}, zh = rh, nh = rh;
    #pragma unroll
    for (int kf = 0; kf < 4; kf++) rh = __builtin_amdgcn_mfma_f32_16x16x32_bf16(Ah[kf], Wh[0][kf], rh, 0,0,0);
    #pragma unroll
    for (int kf = 0; kf < 4; kf++) zh = __builtin_amdgcn_mfma_f32_16x16x32_bf16(Ah[kf], Wh[1][kf], zh, 0,0,0);
    #pragma unroll
    for (int kf = 0; kf < 4; kf++) nh = __builtin_amdgcn_mfma_f32_16x16x32_bf16(Ah[kf], Wh[2][kf], nh, 0,0,0);

    // x-side gate constants (off critical path)
    float cr[4], cz[4], cn[4];
    #pragma unroll
    for (int r = 0; r < 4; r++) { cr[r] = rx[r] + br; cz[r] = zx[r] + bz; cn[r] = nx[r] + bin; }

    // gates: shared-rcp sigmoid pair + exp-based tanh
    unsigned int* hbo = hbw + pout * 1024 + wdw;
    #pragma unroll
    for (int r = 0; r < 4; r++) {
      float er = __expf(-(rh[r] + cr[r]));
      float ez = __expf(-(zh[r] + cz[r]));
      float pr = 1.0f + er, pz = 1.0f + ez;
      float inv = __builtin_amdgcn_rcpf(pr * pz);
      float rr = pz * inv;                  // = 1/(1+er)
      float zz = pr * inv;                  // = 1/(1+ez)
      float y  = cn[r] + rr * (nh[r] + bnh);
      float em = __expf(-2.0f * y);
      float nn = 2.0f * __builtin_amdgcn_rcpf(1.0f + em) - 1.0f;   // tanh(y)
      float hn = nn + zz * (hold[r] - nn);
      hold[r] = hn;
      unsigned short hu = f2bf(hn);
      opq[r * 128] = hu;                                   // global h store
      // packed pair write into LDS (even lane writes b32: cols 2c,2c+1)
      unsigned int hv = (unsigned int)hu;
      unsigned int ov = (unsigned int)__shfl_xor((int)hv, 1);
      if (wlane) hbo[(4 * q + r) * 4] = hv | (ov << 16);
    }
    opq += 131072;                          // advance one timestep (1024*128)
    LDS_BARRIER();
  };

  int s = 0;
  for (; s + 1 < tc; s += 2) { step(s, 0, 1); step(s + 1, 1, 0); }
  if (s < tc) step(s, 0, 1);
}

// ---------------- K2: attention score ----------------
// grid (tc, 2), block 512 (8 waves); each wave: 4 b-tiles of 16 rows.
__global__ __launch_bounds__(512) void k_score(const unsigned short* __restrict__ hl_seq,
                                               const unsigned short* __restrict__ hg_seq,
                                               const unsigned short* __restrict__ a12,
                                               const float* __restrict__ v1,
                                               float* __restrict__ score, int tc)
{
  __shared__ __align__(16) unsigned short M1[128][136];
  __shared__ __align__(16) unsigned short M2[128][136];
  int tid = threadIdx.x;
  int w = tid >> 6, L = tid & 63;
  int l15 = L & 15, q = L >> 4;
  int s = blockIdx.x;
  int bhalf = blockIdx.y * 512;

  // stage A1, A2 (bf16, pre-cast by k_prep) once: 4096 short8 over 512 thr
  #pragma unroll
  for (int it = 0; it < 4; it++) {
    int f8 = it * 512 + tid;                 // 0..2047
    *(short8*)&M1[f8 >> 4][(f8 & 15) * 8] = *(const short8*)(a12 + (size_t)f8 * 8);
    *(short8*)&M2[f8 >> 4][(f8 & 15) * 8] = *(const short8*)(a12 + 16384 + (size_t)f8 * 8);
  }
  __syncthreads();

  float v1v[8];
  #pragma unroll
  for (int nt = 0; nt < 8; nt++) v1v[nt] = v1[nt * 16 + l15];

  // 4 b-tiles per wave, 1-deep fragment prefetch
  short8 Fl[4], Fg[4], Pl[4], Pg[4];
  {
    size_t base = ((size_t)s * 1024 + bhalf + (size_t)w * 16 + l15) * 128;
    #pragma unroll
    for (int kf = 0; kf < 4; kf++) {
      Fl[kf] = *(const short8*)(hl_seq + base + kf * 32 + q * 8);
      Fg[kf] = *(const short8*)(hg_seq + base + kf * 32 + q * 8);
    }
  }
  #pragma unroll
  for (int it = 0; it < 4; it++) {
    int b0 = bhalf + (it * 8 + w) * 16;
    if (it + 1 < 4) {
      size_t base = ((size_t)s * 1024 + bhalf + (size_t)((it + 1) * 8 + w) * 16 + l15) * 128;
      #pragma unroll
      for (int kf = 0; kf < 4; kf++) {
        Pl[kf] = *(const short8*)(hl_seq + base + kf * 32 + q * 8);
        Pg[kf] = *(const short8*)(hg_seq + base + kf * 32 + q * 8);
      }
    }
    float4v acc[8];
    #pragma unroll
    for (int nt = 0; nt < 8; nt++) {
      float4v a = (float4v){0.f, 0.f, 0.f, 0.f};
      #pragma unroll
      for (int kf = 0; kf < 4; kf++)
        a = __builtin_amdgcn_mfma_f32_16x16x32_bf16(
            Fl[kf], *(const short8*)&M1[nt * 16 + l15][kf * 32 + q * 8], a, 0, 0, 0);
      #pragma unroll
      for (int kf = 0; kf < 4; kf++)
        a = __builtin_amdgcn_mfma_f32_16x16x32_bf16(
            Fg[kf], *(const short8*)&M2[nt * 16 + l15][kf * 32 + q * 8], a, 0, 0, 0);
      acc[nt] = a;
    }
    float p4[4];
    #pragma unroll
    for (int r = 0; r < 4; r++) {
      float sum = 0.f;
      #pragma unroll
      for (int nt = 0; nt < 8; nt++) sum += v1v[nt] * sigm(acc[nt][r]);
      sum += __shfl_xor(sum, 1, 16);
      sum += __shfl_xor(sum, 2, 16);
      sum += __shfl_xor(sum, 4, 16);
      sum += __shfl_xor(sum, 8, 16);
      p4[r] = sum;
    }
    if (l15 == 0) {
      #pragma unroll
      for (int r = 0; r < 4; r++)
        score[(size_t)(b0 + q * 4 + r) * tc + s] = p4[r];   // layout [b][tc]
    }
    #pragma unroll
    for (int kf = 0; kf < 4; kf++) { Fl[kf] = Pl[kf]; Fg[kf] = Pg[kf]; }
  }
}

// ---------------- K3: cumsum + capture (LDS-staged) ----------------
// grid 512, block 256: 2 batch rows/block, thread = (b2, j)
__global__ __launch_bounds__(256) void k_cum(const float* __restrict__ score,
                                             const unsigned short* __restrict__ hl_seq,
                                             const unsigned short* __restrict__ hg_seq,
                                             const int* __restrict__ lengths,
                                             float* __restrict__ cum,
                                             float* __restrict__ out, int tc, int t0)
{
  __shared__ __align__(16) unsigned short hlL[100 * 256];  // [s_seg][b2*128+j]
  __shared__ float scL[2][100];
  int tid = threadIdx.x;
  int b2 = tid >> 7, j = tid & 127;
  int b0 = blockIdx.x * 2;
  int b = b0 + b2;
  int base = b2 * 128 + j;

  float c = cum[(size_t)b * 128 + j];
  int cap0 = lengths[b] - 4;                // capture window [cap0, cap0+3] in [0,199]

  // preload the (<=4) h_g capture values that fall in this chunk
  float hgv[4];
  #pragma unroll
  for (int d = 0; d < 4; d++) {
    int sl = cap0 + d - t0;
    hgv[d] = (sl >= 0 && sl < tc) ? bf2f(hg_seq[((size_t)sl * 1024 + b) * 128 + j]) : 0.f;
  }

  for (int seg = 0; seg < tc; seg += 100) {
    int len = (tc - seg < 100) ? (tc - seg) : 100;
    __syncthreads();                         // protect LDS reuse across segments
    // stage hl rows [seg, seg+len) : coalesced short8
    for (int f8 = tid; f8 < len * 32; f8 += 256) {
      int sl = f8 >> 5, r8 = f8 & 31;
      *(short8*)&hlL[(size_t)f8 * 8] =
          *(const short8*)(hl_seq + ((size_t)(seg + sl) * 1024 + b0) * 128 + r8 * 8);
    }
    // stage score rows (contiguous per b: layout [b][tc])
    for (int i = tid; i < 2 * len; i += 256) {
      int bb = (i >= len) ? 1 : 0;
      int sl = i - bb * len;
      scL[bb][sl] = score[(size_t)(b0 + bb) * tc + seg + sl];
    }
    __syncthreads();

    int sl = 0;
    for (; sl + 5 <= len; sl += 5) {
      float h[5], sc[5];
      #pragma unroll
      for (int k = 0; k < 5; k++) {
        h[k] = bf2f(hlL[(size_t)(sl + k) * 256 + base]);
        sc[k] = scL[b2][sl + k];
      }
      #pragma unroll
      for (int k = 0; k < 5; k++) {
        c += sc[k] * h[k];
        int d = (t0 + seg + sl + k) - cap0;
        if ((unsigned)d < 4u)
          out[((size_t)b * 4 + d) * 128 + j] = c + hgv[d];
      }
    }
    for (; sl < len; sl++) {
      c += scL[b2][sl] * bf2f(hlL[(size_t)sl * 256 + base]);
      int d = (t0 + seg + sl) - cap0;
      if ((unsigned)d < 4u)
        out[((size_t)b * 4 + d) * 128 + j] = c + hgv[d];
    }
  }
  cum[(size_t)b * 128 + j] = c;
}

// ---------------- launch ----------------
extern "C" void kernel_launch(void* const* d_in, const int* in_sizes, int n_in,
                              void* d_out, int out_size, void* d_ws, size_t ws_size,
                              hipStream_t stream)
{
  const float* x     = (const float*)d_in[0];
  const int* lengths = (const int*)d_in[1];
  const float* Wih_g = (const float*)d_in[2];
  const float* Whh_g = (const float*)d_in[3];
  const float* bih_g = (const float*)d_in[4];
  const float* bhh_g = (const float*)d_in[5];
  const float* Wih_l = (const float*)d_in[6];
  const float* Whh_l = (const float*)d_in[7];
  const float* bih_l = (const float*)d_in[8];
  const float* bhh_l = (const float*)d_in[9];
  const float* A1    = (const float*)d_in[10];
  const float* A2    = (const float*)d_in[11];
  const float* v1    = (const float*)d_in[12];
  float* out = (float*)d_out;

  // fixed region: a12 bf16 (64KB) + cum (512KB) + xb bf16 (52.4MB)
  const size_t XB = (size_t)200 * 1024 * 128 * 2;
  const size_t fixed = 65536 + 524288 + XB;
  const int cands[8] = {200, 100, 50, 25, 10, 5, 2, 1};
  int tc = 0;
  for (int i = 0; i < 8; i++) {
    int T = cands[i];
    size_t need = 2 * (size_t)T * 1024 * 128 * 2   // hl, hg bf16
                + (size_t)T * 1024 * 4             // score fp32 [b][tc]
                + fixed;
    if (need <= ws_size) { tc = T; break; }
  }
  if (!tc) return;

  char* wsb = (char*)d_ws;
  size_t o = 0;
  unsigned short* a12 = (unsigned short*)(wsb + o); o += 65536;
  float* cum   = (float*)(wsb + o); o += 524288;
  unsigned short* xb = (unsigned short*)(wsb + o); o += XB;
  unsigned short* hl  = (unsigned short*)(wsb + o); o += (size_t)tc * 1024 * 128 * 2;
  unsigned short* hg  = (unsigned short*)(wsb + o); o += (size_t)tc * 1024 * 128 * 2;
  float* score = (float*)(wsb + o);

  unsigned short* hl_slot = hl + (size_t)(tc - 1) * 1024 * 128;
  unsigned short* hg_slot = hg + (size_t)(tc - 1) * 1024 * 128;

  k_prep<<<512, 256, 0, stream>>>(hl_slot, hg_slot, cum, A1, A2, a12);
  k_xcast<<<12800, 256, 0, stream>>>(x, xb);
  int nch = 200 / tc;
  for (int c = 0; c < nch; c++) {
    k_scan<<<128, 512, 0, stream>>>(xb, Wih_g, Whh_g, bih_g, bhh_g,
                                    Wih_l, Whh_l, bih_l, bhh_l, hl, hg, tc, c * tc);
    k_score<<<dim3(tc, 2), 512, 0, stream>>>(hl, hg, a12, v1, score, tc);
    k_cum<<<512, 256, 0, stream>>>(score, hl, hg, lengths, cum, out, tc, c * tc);
  }
}